// Round 9
// baseline (1070.046 us; speedup 1.0000x reference)
//
#include <hip/hip_runtime.h>
#include <math.h>

#define Bb 16
#define Cc 256
#define Nn 1024
#define Mm 256
#define NHh 8
#define HDd 32
#define HIDh 24
#define NMs (Nn*Mm)
#define TTB 16
#define CHUNK 8
#define EPSf 1e-5f
#define SCALEf 0.17677669529663687f   // 1/sqrt(32)
#define STP 32   // stats padding stride (floats) = 128B cacheline

__device__ __forceinline__ float wave_sum(float v){
#pragma unroll
  for (int off=32; off; off>>=1) v += __shfl_xor(v, off, 64);
  return v;
}
__device__ __forceinline__ float wave_max(float v){
#pragma unroll
  for (int off=32; off; off>>=1) v = fmaxf(v, __shfl_xor(v, off, 64));
  return v;
}
__device__ __forceinline__ float swish_(float x){ return x / (1.f + __expf(-x)); }
__device__ __forceinline__ unsigned short f2bf(float f){
  unsigned u = __float_as_uint(f);
  u += 0x7fffu + ((u >> 16) & 1u);          // round-to-nearest-even
  return (unsigned short)(u >> 16);
}
__device__ __forceinline__ float bfup(unsigned short s){ return __uint_as_float(((unsigned)s) << 16); }
__device__ __forceinline__ float bflo(unsigned u){ return __uint_as_float(u << 16); }
__device__ __forceinline__ float bfhi(unsigned u){ return __uint_as_float(u & 0xffff0000u); }

// ------------- GEMM: out[b,i,j] = sum_k A[b,k,i]*W[j,k] (+bias) -------------
template<int MODE>
__launch_bounds__(256)
__global__ void gemm_tn(const float* __restrict__ A, const float* __restrict__ W,
                        const float* __restrict__ bias, float* __restrict__ O1,
                        float* __restrict__ O2, int Kdim, long sAb, int sAk, int sAi)
{
  __shared__ __align__(16) float As[16][68];
  __shared__ __align__(16) float Ws[16][68];
  const int b  = blockIdx.z;
  const int i0 = blockIdx.x * 64;
  const int j0 = blockIdx.y * 64;
  const int tid = threadIdx.x;
  const int tx = tid & 15, ty = tid >> 4;
  const float* Ab = A + (long)b * sAb;
  float acc[4][4] = {};
  for (int k0 = 0; k0 < Kdim; k0 += 16) {
#pragma unroll
    for (int t = 0; t < 4; t++) {
      int idx = tid + t * 256;
      int kk, ii;
      if (sAi == 1) { kk = idx >> 6; ii = idx & 63; }
      else          { ii = idx >> 4; kk = idx & 15; }
      As[kk][ii] = Ab[(long)(k0 + kk) * sAk + (long)(i0 + ii) * sAi];
    }
#pragma unroll
    for (int t = 0; t < 4; t++) {
      int idx = tid + t * 256;
      int jj = idx & 63, kk = idx >> 6;
      Ws[kk][jj] = W[(long)(j0 + jj) * Kdim + (k0 + kk)];
    }
    __syncthreads();
#pragma unroll
    for (int kk = 0; kk < 16; kk++) {
      const float4 av = *(const float4*)&As[kk][tx * 4];
      const float4 wv = *(const float4*)&Ws[kk][ty * 4];
      const float a4[4] = {av.x, av.y, av.z, av.w};
      const float w4[4] = {wv.x, wv.y, wv.z, wv.w};
#pragma unroll
      for (int u = 0; u < 4; u++)
#pragma unroll
        for (int v = 0; v < 4; v++)
          acc[u][v] = fmaf(a4[u], w4[v], acc[u][v]);
    }
    __syncthreads();
  }
#pragma unroll
  for (int v = 0; v < 4; v++) {
    const int j = j0 + ty * 4 + v;
    if (MODE == 0) {
      const int h = j >> 5, d = j & 31;
      float4 r4 = make_float4(acc[0][v], acc[1][v], acc[2][v], acc[3][v]);
      *(float4*)&O1[(((long)b * NHh + h) * HDd + d) * Nn + i0 + tx * 4] = r4;
    } else if (MODE == 2) {
      const float bb = bias[j];
      float4 r4 = make_float4(acc[0][v] + bb, acc[1][v] + bb, acc[2][v] + bb, acc[3][v] + bb);
      *(float4*)&O1[((long)b * Cc + j) * Nn + i0 + tx * 4] = r4;
    } else {
      const int two = j >> 8, jj = j & 255;
      const int h = jj >> 5, d = jj & 31;
      float* p = two ? O2 : O1;
#pragma unroll
      for (int u = 0; u < 4; u++)
        p[(((long)b * NHh + h) * Mm + (i0 + tx * 4 + u)) * HDd + d] = acc[u][v];
    }
  }
}

// ------------- sv[b,h,d] = sum_m v[b,h,m,d] -------------
__launch_bounds__(256)
__global__ void compute_sv(const float* __restrict__ vb, float* __restrict__ sv)
{
  __shared__ float red[256];
  const int bh = blockIdx.x, tid = threadIdx.x;
  const int d = tid & 31, ch = tid >> 5;
  const float* vp = vb + (long)bh * Mm * HDd;
  float s = 0.f;
  for (int m = ch; m < Mm; m += 8) s += vp[m * HDd + d];
  red[tid] = s;
  __syncthreads();
  if (tid < 32) {
    float t = 0.f;
#pragma unroll
    for (int cc = 0; cc < 8; cc++) t += red[cc * 32 + tid];
    sv[(long)bh * HDd + tid] = t;
  }
}

// ------------- scores + softmax -> attn (bf16) -------------
__launch_bounds__(256)
__global__ void attn_softmax(const float* __restrict__ qhT, const float* __restrict__ kb,
                             const float* __restrict__ rpb, unsigned short* __restrict__ attn)
{
  __shared__ __align__(16) float Ks[Mm][36];
  __shared__ __align__(16) float qs[32][36];
  const int b = blockIdx.z, h = blockIdx.y, n0 = blockIdx.x * 32;
  const int tid = threadIdx.x;
  const float* kp = kb + ((long)b * NHh + h) * Mm * HDd;
#pragma unroll
  for (int u = 0; u < 8; u++) {
    const int f = tid + u * 256;
    const int m = f >> 3, d = (f & 7) * 4;
    *(float4*)&Ks[m][d] = *(const float4*)&kp[m * HDd + d];
  }
  const float* qp = qhT + ((long)b * NHh + h) * HDd * Nn;
#pragma unroll
  for (int u = 0; u < 4; u++) {
    const int idx = tid + u * 256;
    const int nn = idx & 31, dd = idx >> 5;
    qs[nn][dd] = qp[(long)dd * Nn + n0 + nn];
  }
  __syncthreads();
  const int lane = tid & 63, w = tid >> 6;
  const int r0 = w * 8;
  float s[8][4] = {};
#pragma unroll
  for (int dq = 0; dq < 8; dq++) {
    float4 k4[4];
#pragma unroll
    for (int j = 0; j < 4; j++) k4[j] = *(const float4*)&Ks[lane + j * 64][dq * 4];
#pragma unroll
    for (int r = 0; r < 8; r++) {
      const float4 q4 = *(const float4*)&qs[r0 + r][dq * 4];
#pragma unroll
      for (int j = 0; j < 4; j++) {
        s[r][j] = fmaf(q4.x, k4[j].x, s[r][j]);
        s[r][j] = fmaf(q4.y, k4[j].y, s[r][j]);
        s[r][j] = fmaf(q4.z, k4[j].z, s[r][j]);
        s[r][j] = fmaf(q4.w, k4[j].w, s[r][j]);
      }
    }
  }
#pragma unroll
  for (int r = 0; r < 8; r++) {
    const int n = n0 + r0 + r;
    const float* rp = rpb + (long)n * Mm;
    float sc[4];
#pragma unroll
    for (int j = 0; j < 4; j++) sc[j] = fmaf(s[r][j], SCALEf, rp[lane + j * 64]);
    float mx = fmaxf(fmaxf(sc[0], sc[1]), fmaxf(sc[2], sc[3]));
    mx = wave_max(mx);
    float e[4], sum = 0.f;
#pragma unroll
    for (int j = 0; j < 4; j++) { e[j] = __expf(sc[j] - mx); sum += e[j]; }
    sum = wave_sum(sum);
    const float inv = 1.f / sum;
    unsigned short* ap = attn + (((long)b * NHh + h) * Nn + n) * Mm;
#pragma unroll
    for (int j = 0; j < 4; j++) ap[lane + j * 64] = f2bf(e[j] * inv);
  }
}

// ------------- Gram matrix G[b][36*STP] (line-spread atomics) -------------
__launch_bounds__(256)
__global__ void gram_stats(const unsigned short* __restrict__ attn, float* __restrict__ G)
{
  __shared__ float red[36][4];
  const int b = blockIdx.y, tid = threadIdx.x;
  const unsigned short* ap = attn + (long)b * NHh * NMs + (long)blockIdx.x * 2048 + tid * 8;
  float a[8][8];
#pragma unroll
  for (int h = 0; h < 8; h++) {
    const uint4 v = *(const uint4*)&ap[(long)h * NMs];
    a[h][0] = bflo(v.x); a[h][1] = bfhi(v.x); a[h][2] = bflo(v.y); a[h][3] = bfhi(v.y);
    a[h][4] = bflo(v.z); a[h][5] = bfhi(v.z); a[h][6] = bflo(v.w); a[h][7] = bfhi(v.w);
  }
  float g[36];
  int t = 0;
#pragma unroll
  for (int i = 0; i < 8; i++)
#pragma unroll
    for (int j = i; j < 8; j++, t++) {
      float s = 0.f;
#pragma unroll
      for (int m = 0; m < 8; m++) s = fmaf(a[i][m], a[j][m], s);
      g[t] = s;
    }
  const int lane = tid & 63, wid = tid >> 6;
#pragma unroll
  for (int t2 = 0; t2 < 36; t2++) {
    const float s = wave_sum(g[t2]);
    if (lane == 0) red[t2][wid] = s;
  }
  __syncthreads();
  if (tid < 36)
    atomicAdd(&G[((long)b * 36 + tid) * STP],
              red[tid][0] + red[tid][1] + red[tid][2] + red[tid][3]);
}

// ------------- pass B: expand+gn1(from G)+swish -> conv3x3 -> x2(bf16) + gn2 stats ----
// Group-staged LDS ring: 3 rows per barrier (768 threads stage 1 uint4 each),
// 6-slot ring (24 KB), 7 barriers/block instead of 18, 12 KB prefetch in flight.
__launch_bounds__(768)
__global__ void dla_pass_b(const unsigned short* __restrict__ attn,
                           const float* __restrict__ Wexp,
                           const float* __restrict__ g1, const float* __restrict__ b1,
                           const float* __restrict__ G, const float* __restrict__ Wdw,
                           unsigned short* __restrict__ x2, float* __restrict__ stats2c, int b0)
{
  __shared__ __align__(16) unsigned short sl[6][NHh][Mm];   // 6 x 4 KB
  const int tid = threadIdx.x;
  const int wv = tid >> 6, lane = tid & 63;
  const int bc = blockIdx.y, b = b0 + bc;
  const int n0 = blockIdx.x * TTB;
  const int c0 = wv * 2;
  const int g = c0 >> 3;
  // gn1 stats from Gram matrix (mean exact: softmax rows sum to 1)
  float mu, rs;
  {
    const float* Gb = G + (long)b * 36 * STP;
    float sum = 0.f, sumsq = 0.f;
    for (int c = g * 8; c < g * 8 + 8; c++) {
      float w[8];
#pragma unroll
      for (int h = 0; h < 8; h++) w[h] = Wexp[c * 8 + h];
      float wsu = 0.f;
#pragma unroll
      for (int h = 0; h < 8; h++) wsu += w[h];
      sum += wsu;
      float s2 = 0.f;
      int t = 0;
#pragma unroll
      for (int i = 0; i < 8; i++)
#pragma unroll
        for (int j = i; j < 8; j++, t++) {
          const float f = (i == j) ? 1.f : 2.f;
          s2 = fmaf(f * w[i] * w[j], Gb[t * STP], s2);
        }
      sumsq += s2;
    }
    const float cnt = 8.f * NMs;
    mu = sum * ((float)Nn / cnt);
    const float var = sumsq / cnt - mu * mu;
    rs = rsqrtf(var + EPSf);
  }
  float we[2][8], B1f[2], wd[2][9];
#pragma unroll
  for (int j = 0; j < 2; j++) {
    const int c = c0 + j;
    const float A1 = rs * g1[c];
    B1f[j] = b1[c] - mu * A1;
#pragma unroll
    for (int h = 0; h < NHh; h++) we[j][h] = Wexp[c * NHh + h] * A1;
#pragma unroll
    for (int k = 0; k < 9; k++) wd[j][k] = Wdw[c * 9 + k];
  }
  const unsigned short* ab = attn + (long)b * NHh * NMs;
  // stage group gg (rows n0 + gg*3 - 1 .. +1) into slots (gg&1)*3 .. +2
  const int srow = tid >> 8;               // 0..2
  const int swithin = tid & 255;
  const int sh = swithin >> 5, sseg = swithin & 31;
  auto stage_group = [&](int gg) {
    const int nn = n0 + gg * 3 - 1 + srow;
    uint4 v;
    if (nn >= 0 && nn < Nn)
      v = *(const uint4*)&ab[(long)sh * NMs + (long)nn * Mm + sseg * 8];
    else
      v = make_uint4(0u, 0u, 0u, 0u);
    *(uint4*)&sl[(gg & 1) * 3 + srow][sh][sseg * 8] = v;
  };
  float s1[2][4] = {}, s2v[2][4] = {};
  float sm[2] = {}, sq[2] = {};
  stage_group(0);
  __syncthreads();
  for (int gg = 0; gg < 6; gg++) {
    if (gg < 5) stage_group(gg + 1);       // issue loads; barrier below drains them
    const int base = (gg & 1) * 3;
#pragma unroll
    for (int rr = 0; rr < 3; rr++) {
      const int r = gg * 3 + rr - 1;       // -1 .. 16
      const int nn = n0 + r;
      const bool rowv = (nn >= 0 && nn < Nn);
      float af[8][4];
#pragma unroll
      for (int h = 0; h < NHh; h++) {
        const ushort4 v = *(const ushort4*)&sl[base + rr][h][lane * 4];
        af[h][0] = bfup(v.x); af[h][1] = bfup(v.y);
        af[h][2] = bfup(v.z); af[h][3] = bfup(v.w);
      }
#pragma unroll
      for (int j = 0; j < 2; j++) {
        float x1[4];
        if (rowv) {
#pragma unroll
          for (int mi = 0; mi < 4; mi++) {
            float x = B1f[j];
#pragma unroll
            for (int h = 0; h < NHh; h++) x = fmaf(we[j][h], af[h][mi], x);
            x1[mi] = swish_(x);
          }
        } else {
#pragma unroll
          for (int mi = 0; mi < 4; mi++) x1[mi] = 0.f;
        }
        float xl = __shfl_up(x1[3], 1);
        float xr = __shfl_down(x1[0], 1);
        if (lane == 0) xl = 0.f;
        if (lane == 63) xr = 0.f;
        const float L[4]  = {xl, x1[0], x1[1], x1[2]};
        const float Ce[4] = {x1[0], x1[1], x1[2], x1[3]};
        const float R[4]  = {x1[1], x1[2], x1[3], xr};
        float y[4];
#pragma unroll
        for (int mi = 0; mi < 4; mi++) {
          const float u0 = wd[j][0]*L[mi] + wd[j][1]*Ce[mi] + wd[j][2]*R[mi];
          const float u1 = wd[j][3]*L[mi] + wd[j][4]*Ce[mi] + wd[j][5]*R[mi];
          const float u2 = wd[j][6]*L[mi] + wd[j][7]*Ce[mi] + wd[j][8]*R[mi];
          y[mi] = s2v[j][mi] + u2;
          s2v[j][mi] = s1[j][mi] + u1;
          s1[j][mi] = u0;
        }
        if (r >= 1) {
#pragma unroll
          for (int mi = 0; mi < 4; mi++) { sm[j] += y[mi]; sq[j] = fmaf(y[mi], y[mi], sq[j]); }
          ushort4 st;
          st.x = f2bf(y[0]); st.y = f2bf(y[1]); st.z = f2bf(y[2]); st.w = f2bf(y[3]);
          const int nw = n0 + r - 1;
          *(ushort4*)&x2[((long)(bc * Nn + nw) * HIDh + (c0 + j)) * Mm + lane * 4] = st;
        }
      }
    }
    __syncthreads();   // staged group gg+1 complete; group gg slots free for reuse
  }
#pragma unroll
  for (int j = 0; j < 2; j++) {
    const float vs = wave_sum(sm[j]);
    const float vq = wave_sum(sq[j]);
    if (lane == 0) {
      atomicAdd(&stats2c[((long)b * HIDh + c0 + j) * STP], vs);
      atomicAdd(&stats2c[((long)b * HIDh + c0 + j) * STP + 1], vq);
    }
  }
}

// ------------- pass C: gn2+swish + 1x1 reduce -> a2(bf16) + partial gn3 stats -------
__launch_bounds__(256)
__global__ void dla_pass_c(const unsigned short* __restrict__ x2, const float* __restrict__ g2,
                           const float* __restrict__ b2, const float* __restrict__ stats2c,
                           const float* __restrict__ Wred, unsigned short* __restrict__ a2,
                           float* __restrict__ partial3, int b0)
{
  __shared__ float wA[HIDh], wB[HIDh], wrs[HIDh][NHh];
  __shared__ float red2[2][4];
  const int tid = threadIdx.x;
  const int wv = tid >> 6, lane = tid & 63;
  const int bc = blockIdx.y, b = b0 + bc;
  if (tid < HIDh) {
    const int c = tid, g = c >> 3;
    float s = 0.f, q = 0.f;
#pragma unroll
    for (int cc = 0; cc < 8; cc++) {
      s += stats2c[((long)b * HIDh + g * 8 + cc) * STP];
      q += stats2c[((long)b * HIDh + g * 8 + cc) * STP + 1];
    }
    const float cnt = 8.f * NMs;
    const float mu = s / cnt;
    const float var = q / cnt - mu * mu;
    const float A2 = rsqrtf(var + EPSf) * g2[c];
    wA[c] = A2; wB[c] = b2[c] - mu * A2;
  }
  if (tid < HIDh * NHh) {
    const int c = tid >> 3, h = tid & 7;
    wrs[c][h] = Wred[h * HIDh + c];
  }
  __syncthreads();
  const int n = blockIdx.x * 4 + wv;
  const unsigned short* xp = x2 + (long)(bc * Nn + n) * HIDh * Mm + lane * 4;
  float red[NHh][4] = {};
#pragma unroll
  for (int c = 0; c < HIDh; c++) {
    const ushort4 xv = *(const ushort4*)&xp[c * Mm];
    const float Ac = wA[c], Bc = wB[c];
    float sw[4];
    sw[0] = swish_(fmaf(bfup(xv.x), Ac, Bc));
    sw[1] = swish_(fmaf(bfup(xv.y), Ac, Bc));
    sw[2] = swish_(fmaf(bfup(xv.z), Ac, Bc));
    sw[3] = swish_(fmaf(bfup(xv.w), Ac, Bc));
#pragma unroll
    for (int h = 0; h < NHh; h++) {
      const float w = wrs[c][h];
      red[h][0] = fmaf(w, sw[0], red[h][0]);
      red[h][1] = fmaf(w, sw[1], red[h][1]);
      red[h][2] = fmaf(w, sw[2], red[h][2]);
      red[h][3] = fmaf(w, sw[3], red[h][3]);
    }
  }
  float s3 = 0.f, q3 = 0.f;
#pragma unroll
  for (int h = 0; h < NHh; h++) {
    ushort4 st;
    st.x = f2bf(red[h][0]); st.y = f2bf(red[h][1]);
    st.z = f2bf(red[h][2]); st.w = f2bf(red[h][3]);
    *(ushort4*)&a2[(((long)b * NHh + h) * Nn + n) * Mm + lane * 4] = st;
#pragma unroll
    for (int mi = 0; mi < 4; mi++) {
      s3 += red[h][mi]; q3 = fmaf(red[h][mi], red[h][mi], q3);
    }
  }
  s3 = wave_sum(s3); q3 = wave_sum(q3);
  if (lane == 0) { red2[0][wv] = s3; red2[1][wv] = q3; }
  __syncthreads();
  if (tid < 2) {
    float t = red2[tid][0] + red2[tid][1] + red2[tid][2] + red2[tid][3];
    partial3[((long)b * 256 + blockIdx.x) * 2 + tid] = t;
  }
}

// ------------- finalize gn3 stats: reduce partial3[b][256][2] -> stats3[b][2] -------
__launch_bounds__(256)
__global__ void finalize_stats3(const float* __restrict__ partial3, float* __restrict__ stats3)
{
  __shared__ float red2[2][4];
  const int b = blockIdx.x, tid = threadIdx.x;
  const int lane = tid & 63, wv = tid >> 6;
  float s = partial3[((long)b * 256 + tid) * 2];
  float q = partial3[((long)b * 256 + tid) * 2 + 1];
  s = wave_sum(s); q = wave_sum(q);
  if (lane == 0) { red2[0][wv] = s; red2[1][wv] = q; }
  __syncthreads();
  if (tid < 2)
    stats3[b * 2 + tid] = red2[tid][0] + red2[tid][1] + red2[tid][2] + red2[tid][3];
}

// ------------- pv_out: gn3 (folded) + PV -> oT[b,c,n] (coalesced) -------------
__launch_bounds__(256)
__global__ void pv_out(const unsigned short* __restrict__ a2, const float* __restrict__ vb,
                       const float* __restrict__ sv, const float* __restrict__ stats3,
                       const float* __restrict__ g3, const float* __restrict__ b3,
                       float* __restrict__ o)
{
  __shared__ __align__(16) float As[16 * 260];
  __shared__ __align__(16) float Vs[Mm * HDd];
  const int b = blockIdx.z, h = blockIdx.y, n0 = blockIdx.x * 256;
  const int tid = threadIdx.x;
  const float* vp = vb + ((long)b * NHh + h) * Mm * HDd;
#pragma unroll
  for (int u = 0; u < 8; u++) {
    const int f = tid + u * 256;
    ((float4*)Vs)[f] = ((const float4*)vp)[f];
  }
  const unsigned short* ap = a2 + (((long)b * NHh + h) * Nn + n0) * Mm;
  const int tx = tid & 63, ty = tid >> 6;
  float acc[4][8] = {};
  for (int k0 = 0; k0 < Mm; k0 += 16) {
    __syncthreads();
#pragma unroll
    for (int u = 0; u < 2; u++) {
      const int s = tid + u * 256;
      const int row = s >> 1, half = (s & 1) * 8;
      const uint4 pk = *(const uint4*)(ap + (long)row * Mm + k0 + half);
      As[(half + 0) * 260 + row] = bflo(pk.x);
      As[(half + 1) * 260 + row] = bfhi(pk.x);
      As[(half + 2) * 260 + row] = bflo(pk.y);
      As[(half + 3) * 260 + row] = bfhi(pk.y);
      As[(half + 4) * 260 + row] = bflo(pk.z);
      As[(half + 5) * 260 + row] = bfhi(pk.z);
      As[(half + 6) * 260 + row] = bflo(pk.w);
      As[(half + 7) * 260 + row] = bfhi(pk.w);
    }
    __syncthreads();
#pragma unroll
    for (int k = 0; k < 16; k++) {
      const float4 a4 = *(const float4*)&As[k * 260 + tx * 4];
      const float4 w0 = *(const float4*)&Vs[(k0 + k) * HDd + ty * 8];
      const float4 w1 = *(const float4*)&Vs[(k0 + k) * HDd + ty * 8 + 4];
      const float av[4] = {a4.x, a4.y, a4.z, a4.w};
      const float vv[8] = {w0.x, w0.y, w0.z, w0.w, w1.x, w1.y, w1.z, w1.w};
#pragma unroll
      for (int u = 0; u < 4; u++)
#pragma unroll
        for (int v = 0; v < 8; v++)
          acc[u][v] = fmaf(av[u], vv[v], acc[u][v]);
    }
  }
  const float cnt = (float)(NHh * NMs);
  const float mu = stats3[b * 2] / cnt;
  const float var = stats3[b * 2 + 1] / cnt - mu * mu;
  const float r3 = rsqrtf(var + EPSf);
  const float alpha = r3 * g3[h];
  const float beta = b3[h] - mu * alpha;
  float svv[8];
#pragma unroll
  for (int v = 0; v < 8; v++) svv[v] = sv[((long)b * NHh + h) * HDd + ty * 8 + v];
#pragma unroll
  for (int v = 0; v < 8; v++) {
    const int c = h * HDd + ty * 8 + v;
    const float bv = beta * svv[v];
    float4 r4 = make_float4(fmaf(alpha, acc[0][v], bv), fmaf(alpha, acc[1][v], bv),
                            fmaf(alpha, acc[2][v], bv), fmaf(alpha, acc[3][v], bv));
    *(float4*)&o[((long)b * Cc + c) * Nn + n0 + tx * 4] = r4;
  }
}

extern "C" void kernel_launch(void* const* d_in, const int* in_sizes, int n_in,
                              void* d_out, int out_size, void* d_ws, size_t ws_size,
                              hipStream_t stream) {
  const float* q    = (const float*)d_in[0];
  const float* kv   = (const float*)d_in[1];
  const float* Wq   = (const float*)d_in[2];
  const float* Wkv  = (const float*)d_in[3];
  const float* Wp   = (const float*)d_in[4];
  const float* bp   = (const float*)d_in[5];
  const float* rpb  = (const float*)d_in[6];
  const float* Wexp = (const float*)d_in[7];
  const float* g1   = (const float*)d_in[8];
  const float* b1   = (const float*)d_in[9];
  const float* Wdw  = (const float*)d_in[10];
  const float* g2   = (const float*)d_in[11];
  const float* b2   = (const float*)d_in[12];
  const float* Wred = (const float*)d_in[13];
  const float* g3   = (const float*)d_in[14];
  const float* b3   = (const float*)d_in[15];
  float* out = (float*)d_out;

  float* ws = (float*)d_ws;
  size_t off = 0;
  auto alloc = [&](size_t n) { float* p = ws + off; off += n; return p; };
  float* attnf   = alloc((size_t)Bb * NHh * NMs / 2);      // 67.1 MB (bf16)
  float* a2f     = alloc((size_t)Bb * NHh * NMs / 2);      // 67.1 MB (bf16)
  float* big     = alloc((size_t)CHUNK * HIDh * NMs / 2);  // 100.7 MB: qhT -> x2 -> oT
  float* kbuf    = alloc((size_t)Bb * NHh * Mm * HDd);     // 4.2 MB
  float* vbuf    = alloc((size_t)Bb * NHh * Mm * HDd);     // 4.2 MB
  float* sv      = alloc((size_t)Bb * NHh * HDd);
  float* G       = alloc((size_t)Bb * 36 * STP);           // line-spread
  float* stats2c = alloc((size_t)Bb * HIDh * STP);         // line-spread
  float* stats3  = alloc(Bb * 2);
  float* partial3= alloc((size_t)Bb * 256 * 2);            // fully overwritten, no memset
  unsigned short* attn = (unsigned short*)attnf;
  unsigned short* a2 = (unsigned short*)a2f;
  float* qhT = big;                           // dead after attn_softmax
  unsigned short* x2 = (unsigned short*)big;  // alive during DLA chunk loop
  float* oT = big;                            // alive after last pass C

  // zero only the atomic-accumulated buffers (G | stats2c are contiguous)
  hipMemsetAsync(G, 0, (size_t)(Bb * 36 * STP + Bb * HIDh * STP) * sizeof(float), stream);

  gemm_tn<0><<<dim3(Nn / 64, Cc / 64, Bb), 256, 0, stream>>>(
      q, Wq, nullptr, qhT, nullptr, Cc, (long)Cc * Nn, Nn, 1);
  gemm_tn<1><<<dim3(Mm / 64, 512 / 64, Bb), 256, 0, stream>>>(
      kv, Wkv, nullptr, kbuf, vbuf, Cc, (long)Cc * Mm, Mm, 1);
  compute_sv<<<dim3(Bb * NHh), 256, 0, stream>>>(vbuf, sv);
  attn_softmax<<<dim3(Nn / 32, NHh, Bb), 256, 0, stream>>>(qhT, kbuf, rpb, attn);
  gram_stats<<<dim3(NMs / 2048, Bb), 256, 0, stream>>>(attn, G);

  for (int b0 = 0; b0 < Bb; b0 += CHUNK) {
    dla_pass_b<<<dim3(Nn / TTB, CHUNK), 768, 0, stream>>>(
        attn, Wexp, g1, b1, G, Wdw, x2, stats2c, b0);
    dla_pass_c<<<dim3(Nn / 4, CHUNK), 256, 0, stream>>>(
        x2, g2, b2, stats2c, Wred, a2, partial3, b0);
  }
  finalize_stats3<<<dim3(Bb), 256, 0, stream>>>(partial3, stats3);

  pv_out<<<dim3(Nn / 256, NHh, Bb), 256, 0, stream>>>(a2, vbuf, sv, stats3, g3, b3, oT);
  gemm_tn<2><<<dim3(Nn / 64, Cc / 64, Bb), 256, 0, stream>>>(
      oT, Wp, bp, out, nullptr, Cc, (long)Cc * Nn, Nn, 1);
}

// Round 10
// 902.087 us; speedup vs baseline: 1.1862x; 1.1862x over previous
//
#include <hip/hip_runtime.h>
#include <math.h>

#define Bb 16
#define Cc 256
#define Nn 1024
#define Mm 256
#define NHh 8
#define HDd 32
#define HIDh 24
#define NMs (Nn*Mm)
#define TTB 8
#define CHUNK 4
#define EPSf 1e-5f
#define SCALEf 0.17677669529663687f   // 1/sqrt(32)
#define STP 32   // stats padding stride (floats) = 128B cacheline

__device__ __forceinline__ float wave_sum(float v){
#pragma unroll
  for (int off=32; off; off>>=1) v += __shfl_xor(v, off, 64);
  return v;
}
__device__ __forceinline__ float wave_max(float v){
#pragma unroll
  for (int off=32; off; off>>=1) v = fmaxf(v, __shfl_xor(v, off, 64));
  return v;
}
__device__ __forceinline__ float swish_(float x){ return x / (1.f + __expf(-x)); }
__device__ __forceinline__ unsigned short f2bf(float f){
  unsigned u = __float_as_uint(f);
  u += 0x7fffu + ((u >> 16) & 1u);          // round-to-nearest-even
  return (unsigned short)(u >> 16);
}
__device__ __forceinline__ float bfup(unsigned short s){ return __uint_as_float(((unsigned)s) << 16); }
__device__ __forceinline__ float bflo(unsigned u){ return __uint_as_float(u << 16); }
__device__ __forceinline__ float bfhi(unsigned u){ return __uint_as_float(u & 0xffff0000u); }

// ------------- GEMM: out[b,i,j] = sum_k A[b,k,i]*W[j,k] (+bias) -------------
template<int MODE>
__launch_bounds__(256)
__global__ void gemm_tn(const float* __restrict__ A, const float* __restrict__ W,
                        const float* __restrict__ bias, float* __restrict__ O1,
                        float* __restrict__ O2, int Kdim, long sAb, int sAk, int sAi)
{
  __shared__ __align__(16) float As[16][68];
  __shared__ __align__(16) float Ws[16][68];
  const int b  = blockIdx.z;
  const int i0 = blockIdx.x * 64;
  const int j0 = blockIdx.y * 64;
  const int tid = threadIdx.x;
  const int tx = tid & 15, ty = tid >> 4;
  const float* Ab = A + (long)b * sAb;
  float acc[4][4] = {};
  for (int k0 = 0; k0 < Kdim; k0 += 16) {
#pragma unroll
    for (int t = 0; t < 4; t++) {
      int idx = tid + t * 256;
      int kk, ii;
      if (sAi == 1) { kk = idx >> 6; ii = idx & 63; }
      else          { ii = idx >> 4; kk = idx & 15; }
      As[kk][ii] = Ab[(long)(k0 + kk) * sAk + (long)(i0 + ii) * sAi];
    }
#pragma unroll
    for (int t = 0; t < 4; t++) {
      int idx = tid + t * 256;
      int jj = idx & 63, kk = idx >> 6;
      Ws[kk][jj] = W[(long)(j0 + jj) * Kdim + (k0 + kk)];
    }
    __syncthreads();
#pragma unroll
    for (int kk = 0; kk < 16; kk++) {
      const float4 av = *(const float4*)&As[kk][tx * 4];
      const float4 wv = *(const float4*)&Ws[kk][ty * 4];
      const float a4[4] = {av.x, av.y, av.z, av.w};
      const float w4[4] = {wv.x, wv.y, wv.z, wv.w};
#pragma unroll
      for (int u = 0; u < 4; u++)
#pragma unroll
        for (int v = 0; v < 4; v++)
          acc[u][v] = fmaf(a4[u], w4[v], acc[u][v]);
    }
    __syncthreads();
  }
#pragma unroll
  for (int v = 0; v < 4; v++) {
    const int j = j0 + ty * 4 + v;
    if (MODE == 0) {
      const int h = j >> 5, d = j & 31;
      float4 r4 = make_float4(acc[0][v], acc[1][v], acc[2][v], acc[3][v]);
      *(float4*)&O1[(((long)b * NHh + h) * HDd + d) * Nn + i0 + tx * 4] = r4;
    } else if (MODE == 2) {
      const float bb = bias[j];
      float4 r4 = make_float4(acc[0][v] + bb, acc[1][v] + bb, acc[2][v] + bb, acc[3][v] + bb);
      *(float4*)&O1[((long)b * Cc + j) * Nn + i0 + tx * 4] = r4;
    } else {
      const int two = j >> 8, jj = j & 255;
      const int h = jj >> 5, d = jj & 31;
      float* p = two ? O2 : O1;
#pragma unroll
      for (int u = 0; u < 4; u++)
        p[(((long)b * NHh + h) * Mm + (i0 + tx * 4 + u)) * HDd + d] = acc[u][v];
    }
  }
}

// ------------- sv[b,h,d] = sum_m v[b,h,m,d] -------------
__launch_bounds__(256)
__global__ void compute_sv(const float* __restrict__ vb, float* __restrict__ sv)
{
  __shared__ float red[256];
  const int bh = blockIdx.x, tid = threadIdx.x;
  const int d = tid & 31, ch = tid >> 5;
  const float* vp = vb + (long)bh * Mm * HDd;
  float s = 0.f;
  for (int m = ch; m < Mm; m += 8) s += vp[m * HDd + d];
  red[tid] = s;
  __syncthreads();
  if (tid < 32) {
    float t = 0.f;
#pragma unroll
    for (int cc = 0; cc < 8; cc++) t += red[cc * 32 + tid];
    sv[(long)bh * HDd + tid] = t;
  }
}

// ------------- scores + softmax -> attn (bf16) -------------
__launch_bounds__(256)
__global__ void attn_softmax(const float* __restrict__ qhT, const float* __restrict__ kb,
                             const float* __restrict__ rpb, unsigned short* __restrict__ attn)
{
  __shared__ __align__(16) float Ks[Mm][36];
  __shared__ __align__(16) float qs[32][36];
  const int b = blockIdx.z, h = blockIdx.y, n0 = blockIdx.x * 32;
  const int tid = threadIdx.x;
  const float* kp = kb + ((long)b * NHh + h) * Mm * HDd;
#pragma unroll
  for (int u = 0; u < 8; u++) {
    const int f = tid + u * 256;
    const int m = f >> 3, d = (f & 7) * 4;
    *(float4*)&Ks[m][d] = *(const float4*)&kp[m * HDd + d];
  }
  const float* qp = qhT + ((long)b * NHh + h) * HDd * Nn;
#pragma unroll
  for (int u = 0; u < 4; u++) {
    const int idx = tid + u * 256;
    const int nn = idx & 31, dd = idx >> 5;
    qs[nn][dd] = qp[(long)dd * Nn + n0 + nn];
  }
  __syncthreads();
  const int lane = tid & 63, w = tid >> 6;
  const int r0 = w * 8;
  float s[8][4] = {};
#pragma unroll
  for (int dq = 0; dq < 8; dq++) {
    float4 k4[4];
#pragma unroll
    for (int j = 0; j < 4; j++) k4[j] = *(const float4*)&Ks[lane + j * 64][dq * 4];
#pragma unroll
    for (int r = 0; r < 8; r++) {
      const float4 q4 = *(const float4*)&qs[r0 + r][dq * 4];
#pragma unroll
      for (int j = 0; j < 4; j++) {
        s[r][j] = fmaf(q4.x, k4[j].x, s[r][j]);
        s[r][j] = fmaf(q4.y, k4[j].y, s[r][j]);
        s[r][j] = fmaf(q4.z, k4[j].z, s[r][j]);
        s[r][j] = fmaf(q4.w, k4[j].w, s[r][j]);
      }
    }
  }
#pragma unroll
  for (int r = 0; r < 8; r++) {
    const int n = n0 + r0 + r;
    const float* rp = rpb + (long)n * Mm;
    float sc[4];
#pragma unroll
    for (int j = 0; j < 4; j++) sc[j] = fmaf(s[r][j], SCALEf, rp[lane + j * 64]);
    float mx = fmaxf(fmaxf(sc[0], sc[1]), fmaxf(sc[2], sc[3]));
    mx = wave_max(mx);
    float e[4], sum = 0.f;
#pragma unroll
    for (int j = 0; j < 4; j++) { e[j] = __expf(sc[j] - mx); sum += e[j]; }
    sum = wave_sum(sum);
    const float inv = 1.f / sum;
    unsigned short* ap = attn + (((long)b * NHh + h) * Nn + n) * Mm;
#pragma unroll
    for (int j = 0; j < 4; j++) ap[lane + j * 64] = f2bf(e[j] * inv);
  }
}

// ------------- Gram matrix G[b][36*STP] (line-spread atomics) -------------
__launch_bounds__(256)
__global__ void gram_stats(const unsigned short* __restrict__ attn, float* __restrict__ G)
{
  __shared__ float red[36][4];
  const int b = blockIdx.y, tid = threadIdx.x;
  const unsigned short* ap = attn + (long)b * NHh * NMs + (long)blockIdx.x * 2048 + tid * 8;
  float a[8][8];
#pragma unroll
  for (int h = 0; h < 8; h++) {
    const uint4 v = *(const uint4*)&ap[(long)h * NMs];
    a[h][0] = bflo(v.x); a[h][1] = bfhi(v.x); a[h][2] = bflo(v.y); a[h][3] = bfhi(v.y);
    a[h][4] = bflo(v.z); a[h][5] = bfhi(v.z); a[h][6] = bflo(v.w); a[h][7] = bfhi(v.w);
  }
  float g[36];
  int t = 0;
#pragma unroll
  for (int i = 0; i < 8; i++)
#pragma unroll
    for (int j = i; j < 8; j++, t++) {
      float s = 0.f;
#pragma unroll
      for (int m = 0; m < 8; m++) s = fmaf(a[i][m], a[j][m], s);
      g[t] = s;
    }
  const int lane = tid & 63, wid = tid >> 6;
#pragma unroll
  for (int t2 = 0; t2 < 36; t2++) {
    const float s = wave_sum(g[t2]);
    if (lane == 0) red[t2][wid] = s;
  }
  __syncthreads();
  if (tid < 36)
    atomicAdd(&G[((long)b * 36 + tid) * STP],
              red[tid][0] + red[tid][1] + red[tid][2] + red[tid][3]);
}

// ------------- pass B: expand+gn1(from G)+swish -> conv3x3 -> x2(bf16) + gn2 stats ----
// R8's proven traffic-clean 2-slot ring; TTB=8 so grid=512 blocks -> 2 blocks/CU,
// letting one block's compute hide the other block's per-row barrier stall.
__launch_bounds__(768)
__global__ void dla_pass_b(const unsigned short* __restrict__ attn,
                           const float* __restrict__ Wexp,
                           const float* __restrict__ g1, const float* __restrict__ b1,
                           const float* __restrict__ G, const float* __restrict__ Wdw,
                           unsigned short* __restrict__ x2, float* __restrict__ stats2c, int b0)
{
  __shared__ __align__(16) unsigned short sl[2][NHh][Mm];   // 2 x 4 KB
  const int tid = threadIdx.x;
  const int wv = tid >> 6, lane = tid & 63;
  const int bc = blockIdx.y, b = b0 + bc;
  const int n0 = blockIdx.x * TTB;
  const int c0 = wv * 2;
  const int g = c0 >> 3;
  // gn1 stats from Gram matrix (mean exact: softmax rows sum to 1)
  float mu, rs;
  {
    const float* Gb = G + (long)b * 36 * STP;
    float sum = 0.f, sumsq = 0.f;
    for (int c = g * 8; c < g * 8 + 8; c++) {
      float w[8];
#pragma unroll
      for (int h = 0; h < 8; h++) w[h] = Wexp[c * 8 + h];
      float wsu = 0.f;
#pragma unroll
      for (int h = 0; h < 8; h++) wsu += w[h];
      sum += wsu;
      float s2 = 0.f;
      int t = 0;
#pragma unroll
      for (int i = 0; i < 8; i++)
#pragma unroll
        for (int j = i; j < 8; j++, t++) {
          const float f = (i == j) ? 1.f : 2.f;
          s2 = fmaf(f * w[i] * w[j], Gb[t * STP], s2);
        }
      sumsq += s2;
    }
    const float cnt = 8.f * NMs;
    mu = sum * ((float)Nn / cnt);
    const float var = sumsq / cnt - mu * mu;
    rs = rsqrtf(var + EPSf);
  }
  float we[2][8], B1f[2], wd[2][9];
#pragma unroll
  for (int j = 0; j < 2; j++) {
    const int c = c0 + j;
    const float A1 = rs * g1[c];
    B1f[j] = b1[c] - mu * A1;
#pragma unroll
    for (int h = 0; h < NHh; h++) we[j][h] = Wexp[c * NHh + h] * A1;
#pragma unroll
    for (int k = 0; k < 9; k++) wd[j][k] = Wdw[c * 9 + k];
  }
  const unsigned short* ab = attn + (long)b * NHh * NMs;
  auto stage = [&](int s, int nn) {
    if (tid < 256) {
      const int h = tid >> 5, seg = tid & 31;
      uint4 v;
      if (nn >= 0 && nn < Nn)
        v = *(const uint4*)&ab[(long)h * NMs + (long)nn * Mm + seg * 8];
      else
        v = make_uint4(0u, 0u, 0u, 0u);
      *(uint4*)&sl[s][h][seg * 8] = v;
    }
  };
  float s1[2][4] = {}, s2v[2][4] = {};
  float sm[2] = {}, sq[2] = {};
  stage(0, n0 - 1);
  __syncthreads();
  for (int r = -1; r <= TTB; r++) {
    const int cur = (r + 1) & 1;
    if (r < TTB) stage((r + 2) & 1, n0 + r + 1);
    const int nn = n0 + r;
    const bool rowv = (nn >= 0 && nn < Nn);
    float af[8][4];
#pragma unroll
    for (int h = 0; h < NHh; h++) {
      const ushort4 v = *(const ushort4*)&sl[cur][h][lane * 4];
      af[h][0] = bfup(v.x); af[h][1] = bfup(v.y);
      af[h][2] = bfup(v.z); af[h][3] = bfup(v.w);
    }
#pragma unroll
    for (int j = 0; j < 2; j++) {
      float x1[4];
      if (rowv) {
#pragma unroll
        for (int mi = 0; mi < 4; mi++) {
          float x = B1f[j];
#pragma unroll
          for (int h = 0; h < NHh; h++) x = fmaf(we[j][h], af[h][mi], x);
          x1[mi] = swish_(x);
        }
      } else {
#pragma unroll
        for (int mi = 0; mi < 4; mi++) x1[mi] = 0.f;
      }
      float xl = __shfl_up(x1[3], 1);
      float xr = __shfl_down(x1[0], 1);
      if (lane == 0) xl = 0.f;
      if (lane == 63) xr = 0.f;
      const float L[4]  = {xl, x1[0], x1[1], x1[2]};
      const float Ce[4] = {x1[0], x1[1], x1[2], x1[3]};
      const float R[4]  = {x1[1], x1[2], x1[3], xr};
      float y[4];
#pragma unroll
      for (int mi = 0; mi < 4; mi++) {
        const float u0 = wd[j][0]*L[mi] + wd[j][1]*Ce[mi] + wd[j][2]*R[mi];
        const float u1 = wd[j][3]*L[mi] + wd[j][4]*Ce[mi] + wd[j][5]*R[mi];
        const float u2 = wd[j][6]*L[mi] + wd[j][7]*Ce[mi] + wd[j][8]*R[mi];
        y[mi] = s2v[j][mi] + u2;
        s2v[j][mi] = s1[j][mi] + u1;
        s1[j][mi] = u0;
      }
      if (r >= 1) {
#pragma unroll
        for (int mi = 0; mi < 4; mi++) { sm[j] += y[mi]; sq[j] = fmaf(y[mi], y[mi], sq[j]); }
        ushort4 st;
        st.x = f2bf(y[0]); st.y = f2bf(y[1]); st.z = f2bf(y[2]); st.w = f2bf(y[3]);
        const int nw = n0 + r - 1;
        *(ushort4*)&x2[((long)(bc * Nn + nw) * HIDh + (c0 + j)) * Mm + lane * 4] = st;
      }
    }
    __syncthreads();
  }
#pragma unroll
  for (int j = 0; j < 2; j++) {
    const float vs = wave_sum(sm[j]);
    const float vq = wave_sum(sq[j]);
    if (lane == 0) {
      atomicAdd(&stats2c[((long)b * HIDh + c0 + j) * STP], vs);
      atomicAdd(&stats2c[((long)b * HIDh + c0 + j) * STP + 1], vq);
    }
  }
}

// ------------- pass C: gn2+swish + 1x1 reduce -> a2(bf16) + partial gn3 stats -------
__launch_bounds__(256)
__global__ void dla_pass_c(const unsigned short* __restrict__ x2, const float* __restrict__ g2,
                           const float* __restrict__ b2, const float* __restrict__ stats2c,
                           const float* __restrict__ Wred, unsigned short* __restrict__ a2,
                           float* __restrict__ partial3, int b0)
{
  __shared__ float wA[HIDh], wB[HIDh], wrs[HIDh][NHh];
  __shared__ float red2[2][4];
  const int tid = threadIdx.x;
  const int wv = tid >> 6, lane = tid & 63;
  const int bc = blockIdx.y, b = b0 + bc;
  if (tid < HIDh) {
    const int c = tid, g = c >> 3;
    float s = 0.f, q = 0.f;
#pragma unroll
    for (int cc = 0; cc < 8; cc++) {
      s += stats2c[((long)b * HIDh + g * 8 + cc) * STP];
      q += stats2c[((long)b * HIDh + g * 8 + cc) * STP + 1];
    }
    const float cnt = 8.f * NMs;
    const float mu = s / cnt;
    const float var = q / cnt - mu * mu;
    const float A2 = rsqrtf(var + EPSf) * g2[c];
    wA[c] = A2; wB[c] = b2[c] - mu * A2;
  }
  if (tid < HIDh * NHh) {
    const int c = tid >> 3, h = tid & 7;
    wrs[c][h] = Wred[h * HIDh + c];
  }
  __syncthreads();
  const int n = blockIdx.x * 4 + wv;
  const unsigned short* xp = x2 + (long)(bc * Nn + n) * HIDh * Mm + lane * 4;
  float red[NHh][4] = {};
#pragma unroll
  for (int c = 0; c < HIDh; c++) {
    const ushort4 xv = *(const ushort4*)&xp[c * Mm];
    const float Ac = wA[c], Bc = wB[c];
    float sw[4];
    sw[0] = swish_(fmaf(bfup(xv.x), Ac, Bc));
    sw[1] = swish_(fmaf(bfup(xv.y), Ac, Bc));
    sw[2] = swish_(fmaf(bfup(xv.z), Ac, Bc));
    sw[3] = swish_(fmaf(bfup(xv.w), Ac, Bc));
#pragma unroll
    for (int h = 0; h < NHh; h++) {
      const float w = wrs[c][h];
      red[h][0] = fmaf(w, sw[0], red[h][0]);
      red[h][1] = fmaf(w, sw[1], red[h][1]);
      red[h][2] = fmaf(w, sw[2], red[h][2]);
      red[h][3] = fmaf(w, sw[3], red[h][3]);
    }
  }
  float s3 = 0.f, q3 = 0.f;
#pragma unroll
  for (int h = 0; h < NHh; h++) {
    ushort4 st;
    st.x = f2bf(red[h][0]); st.y = f2bf(red[h][1]);
    st.z = f2bf(red[h][2]); st.w = f2bf(red[h][3]);
    *(ushort4*)&a2[(((long)b * NHh + h) * Nn + n) * Mm + lane * 4] = st;
#pragma unroll
    for (int mi = 0; mi < 4; mi++) {
      s3 += red[h][mi]; q3 = fmaf(red[h][mi], red[h][mi], q3);
    }
  }
  s3 = wave_sum(s3); q3 = wave_sum(q3);
  if (lane == 0) { red2[0][wv] = s3; red2[1][wv] = q3; }
  __syncthreads();
  if (tid < 2) {
    float t = red2[tid][0] + red2[tid][1] + red2[tid][2] + red2[tid][3];
    partial3[((long)b * 256 + blockIdx.x) * 2 + tid] = t;
  }
}

// ------------- finalize gn3 stats: reduce partial3[b][256][2] -> stats3[b][2] -------
__launch_bounds__(256)
__global__ void finalize_stats3(const float* __restrict__ partial3, float* __restrict__ stats3)
{
  __shared__ float red2[2][4];
  const int b = blockIdx.x, tid = threadIdx.x;
  const int lane = tid & 63, wv = tid >> 6;
  float s = partial3[((long)b * 256 + tid) * 2];
  float q = partial3[((long)b * 256 + tid) * 2 + 1];
  s = wave_sum(s); q = wave_sum(q);
  if (lane == 0) { red2[0][wv] = s; red2[1][wv] = q; }
  __syncthreads();
  if (tid < 2)
    stats3[b * 2 + tid] = red2[tid][0] + red2[tid][1] + red2[tid][2] + red2[tid][3];
}

// ------------- pv_out: gn3 (folded) + PV -> oT[b,c,n] (coalesced) -------------
__launch_bounds__(256)
__global__ void pv_out(const unsigned short* __restrict__ a2, const float* __restrict__ vb,
                       const float* __restrict__ sv, const float* __restrict__ stats3,
                       const float* __restrict__ g3, const float* __restrict__ b3,
                       float* __restrict__ o)
{
  __shared__ __align__(16) float As[16 * 260];
  __shared__ __align__(16) float Vs[Mm * HDd];
  const int b = blockIdx.z, h = blockIdx.y, n0 = blockIdx.x * 256;
  const int tid = threadIdx.x;
  const float* vp = vb + ((long)b * NHh + h) * Mm * HDd;
#pragma unroll
  for (int u = 0; u < 8; u++) {
    const int f = tid + u * 256;
    ((float4*)Vs)[f] = ((const float4*)vp)[f];
  }
  const unsigned short* ap = a2 + (((long)b * NHh + h) * Nn + n0) * Mm;
  const int tx = tid & 63, ty = tid >> 6;
  float acc[4][8] = {};
  for (int k0 = 0; k0 < Mm; k0 += 16) {
    __syncthreads();
#pragma unroll
    for (int u = 0; u < 2; u++) {
      const int s = tid + u * 256;
      const int row = s >> 1, half = (s & 1) * 8;
      const uint4 pk = *(const uint4*)(ap + (long)row * Mm + k0 + half);
      As[(half + 0) * 260 + row] = bflo(pk.x);
      As[(half + 1) * 260 + row] = bfhi(pk.x);
      As[(half + 2) * 260 + row] = bflo(pk.y);
      As[(half + 3) * 260 + row] = bfhi(pk.y);
      As[(half + 4) * 260 + row] = bflo(pk.z);
      As[(half + 5) * 260 + row] = bfhi(pk.z);
      As[(half + 6) * 260 + row] = bflo(pk.w);
      As[(half + 7) * 260 + row] = bfhi(pk.w);
    }
    __syncthreads();
#pragma unroll
    for (int k = 0; k < 16; k++) {
      const float4 a4 = *(const float4*)&As[k * 260 + tx * 4];
      const float4 w0 = *(const float4*)&Vs[(k0 + k) * HDd + ty * 8];
      const float4 w1 = *(const float4*)&Vs[(k0 + k) * HDd + ty * 8 + 4];
      const float av[4] = {a4.x, a4.y, a4.z, a4.w};
      const float vv[8] = {w0.x, w0.y, w0.z, w0.w, w1.x, w1.y, w1.z, w1.w};
#pragma unroll
      for (int u = 0; u < 4; u++)
#pragma unroll
        for (int v = 0; v < 8; v++)
          acc[u][v] = fmaf(av[u], vv[v], acc[u][v]);
    }
  }
  const float cnt = (float)(NHh * NMs);
  const float mu = stats3[b * 2] / cnt;
  const float var = stats3[b * 2 + 1] / cnt - mu * mu;
  const float r3 = rsqrtf(var + EPSf);
  const float alpha = r3 * g3[h];
  const float beta = b3[h] - mu * alpha;
  float svv[8];
#pragma unroll
  for (int v = 0; v < 8; v++) svv[v] = sv[((long)b * NHh + h) * HDd + ty * 8 + v];
#pragma unroll
  for (int v = 0; v < 8; v++) {
    const int c = h * HDd + ty * 8 + v;
    const float bv = beta * svv[v];
    float4 r4 = make_float4(fmaf(alpha, acc[0][v], bv), fmaf(alpha, acc[1][v], bv),
                            fmaf(alpha, acc[2][v], bv), fmaf(alpha, acc[3][v], bv));
    *(float4*)&o[((long)b * Cc + c) * Nn + n0 + tx * 4] = r4;
  }
}

extern "C" void kernel_launch(void* const* d_in, const int* in_sizes, int n_in,
                              void* d_out, int out_size, void* d_ws, size_t ws_size,
                              hipStream_t stream) {
  const float* q    = (const float*)d_in[0];
  const float* kv   = (const float*)d_in[1];
  const float* Wq   = (const float*)d_in[2];
  const float* Wkv  = (const float*)d_in[3];
  const float* Wp   = (const float*)d_in[4];
  const float* bp   = (const float*)d_in[5];
  const float* rpb  = (const float*)d_in[6];
  const float* Wexp = (const float*)d_in[7];
  const float* g1   = (const float*)d_in[8];
  const float* b1   = (const float*)d_in[9];
  const float* Wdw  = (const float*)d_in[10];
  const float* g2   = (const float*)d_in[11];
  const float* b2   = (const float*)d_in[12];
  const float* Wred = (const float*)d_in[13];
  const float* g3   = (const float*)d_in[14];
  const float* b3   = (const float*)d_in[15];
  float* out = (float*)d_out;

  float* ws = (float*)d_ws;
  size_t off = 0;
  auto alloc = [&](size_t n) { float* p = ws + off; off += n; return p; };
  float* attnf   = alloc((size_t)Bb * NHh * NMs / 2);      // 67.1 MB (bf16)
  float* a2f     = alloc((size_t)Bb * NHh * NMs / 2);      // 67.1 MB (bf16)
  float* big     = alloc((size_t)CHUNK * HIDh * NMs / 2);  // 50.3 MB: qhT -> x2 -> oT
  float* kbuf    = alloc((size_t)Bb * NHh * Mm * HDd);     // 4.2 MB
  float* vbuf    = alloc((size_t)Bb * NHh * Mm * HDd);     // 4.2 MB
  float* sv      = alloc((size_t)Bb * NHh * HDd);
  float* G       = alloc((size_t)Bb * 36 * STP);           // line-spread
  float* stats2c = alloc((size_t)Bb * HIDh * STP);         // line-spread
  float* stats3  = alloc(Bb * 2);
  float* partial3= alloc((size_t)Bb * 256 * 2);            // fully overwritten, no memset
  unsigned short* attn = (unsigned short*)attnf;
  unsigned short* a2 = (unsigned short*)a2f;
  float* qhT = big;                           // dead after attn_softmax
  unsigned short* x2 = (unsigned short*)big;  // alive during DLA chunk loop
  float* oT = big;                            // alive after last pass C

  // zero only the atomic-accumulated buffers (G | stats2c are contiguous)
  hipMemsetAsync(G, 0, (size_t)(Bb * 36 * STP + Bb * HIDh * STP) * sizeof(float), stream);

  gemm_tn<0><<<dim3(Nn / 64, Cc / 64, Bb), 256, 0, stream>>>(
      q, Wq, nullptr, qhT, nullptr, Cc, (long)Cc * Nn, Nn, 1);
  gemm_tn<1><<<dim3(Mm / 64, 512 / 64, Bb), 256, 0, stream>>>(
      kv, Wkv, nullptr, kbuf, vbuf, Cc, (long)Cc * Mm, Mm, 1);
  compute_sv<<<dim3(Bb * NHh), 256, 0, stream>>>(vbuf, sv);
  attn_softmax<<<dim3(Nn / 32, NHh, Bb), 256, 0, stream>>>(qhT, kbuf, rpb, attn);
  gram_stats<<<dim3(NMs / 2048, Bb), 256, 0, stream>>>(attn, G);

  for (int b0 = 0; b0 < Bb; b0 += CHUNK) {
    dla_pass_b<<<dim3(Nn / TTB, CHUNK), 768, 0, stream>>>(
        attn, Wexp, g1, b1, G, Wdw, x2, stats2c, b0);
    dla_pass_c<<<dim3(Nn / 4, CHUNK), 256, 0, stream>>>(
        x2, g2, b2, stats2c, Wred, a2, partial3, b0);
  }
  finalize_stats3<<<dim3(Bb), 256, 0, stream>>>(partial3, stats3);

  pv_out<<<dim3(Nn / 256, NHh, Bb), 256, 0, stream>>>(a2, vbuf, sv, stats3, g3, b3, oT);
  gemm_tn<2><<<dim3(Nn / 64, Cc / 64, Bb), 256, 0, stream>>>(
      oT, Wp, bp, out, nullptr, Cc, (long)Cc * Nn, Nn, 1);
}

// Round 11
// 600.470 us; speedup vs baseline: 1.7820x; 1.5023x over previous
//
#include <hip/hip_runtime.h>
#include <math.h>

#define Bb 16
#define Cc 256
#define Nn 1024
#define Mm 256
#define NHh 8
#define HDd 32
#define HIDh 24
#define NMs (Nn*Mm)
#define TTB 16
#define CHUNK 8
#define EPSf 1e-5f
#define SCALEf 0.17677669529663687f   // 1/sqrt(32)
#define STP 32   // stats padding stride (floats) = 128B cacheline

__device__ __forceinline__ float wave_sum(float v){
#pragma unroll
  for (int off=32; off; off>>=1) v += __shfl_xor(v, off, 64);
  return v;
}
__device__ __forceinline__ float wave_max(float v){
#pragma unroll
  for (int off=32; off; off>>=1) v = fmaxf(v, __shfl_xor(v, off, 64));
  return v;
}
__device__ __forceinline__ float swish_(float x){ return x / (1.f + __expf(-x)); }
__device__ __forceinline__ unsigned short f2bf(float f){
  unsigned u = __float_as_uint(f);
  u += 0x7fffu + ((u >> 16) & 1u);          // round-to-nearest-even
  return (unsigned short)(u >> 16);
}
__device__ __forceinline__ float bfup(unsigned short s){ return __uint_as_float(((unsigned)s) << 16); }
__device__ __forceinline__ float bflo(unsigned u){ return __uint_as_float(u << 16); }
__device__ __forceinline__ float bfhi(unsigned u){ return __uint_as_float(u & 0xffff0000u); }

// ------------- GEMM: out[b,i,j] = sum_k A[b,k,i]*W[j,k] (+bias) -------------
template<int MODE>
__launch_bounds__(256)
__global__ void gemm_tn(const float* __restrict__ A, const float* __restrict__ W,
                        const float* __restrict__ bias, float* __restrict__ O1,
                        float* __restrict__ O2, int Kdim, long sAb, int sAk, int sAi)
{
  __shared__ __align__(16) float As[16][68];
  __shared__ __align__(16) float Ws[16][68];
  const int b  = blockIdx.z;
  const int i0 = blockIdx.x * 64;
  const int j0 = blockIdx.y * 64;
  const int tid = threadIdx.x;
  const int tx = tid & 15, ty = tid >> 4;
  const float* Ab = A + (long)b * sAb;
  float acc[4][4] = {};
  for (int k0 = 0; k0 < Kdim; k0 += 16) {
#pragma unroll
    for (int t = 0; t < 4; t++) {
      int idx = tid + t * 256;
      int kk, ii;
      if (sAi == 1) { kk = idx >> 6; ii = idx & 63; }
      else          { ii = idx >> 4; kk = idx & 15; }
      As[kk][ii] = Ab[(long)(k0 + kk) * sAk + (long)(i0 + ii) * sAi];
    }
#pragma unroll
    for (int t = 0; t < 4; t++) {
      int idx = tid + t * 256;
      int jj = idx & 63, kk = idx >> 6;
      Ws[kk][jj] = W[(long)(j0 + jj) * Kdim + (k0 + kk)];
    }
    __syncthreads();
#pragma unroll
    for (int kk = 0; kk < 16; kk++) {
      const float4 av = *(const float4*)&As[kk][tx * 4];
      const float4 wv = *(const float4*)&Ws[kk][ty * 4];
      const float a4[4] = {av.x, av.y, av.z, av.w};
      const float w4[4] = {wv.x, wv.y, wv.z, wv.w};
#pragma unroll
      for (int u = 0; u < 4; u++)
#pragma unroll
        for (int v = 0; v < 4; v++)
          acc[u][v] = fmaf(a4[u], w4[v], acc[u][v]);
    }
    __syncthreads();
  }
#pragma unroll
  for (int v = 0; v < 4; v++) {
    const int j = j0 + ty * 4 + v;
    if (MODE == 0) {
      const int h = j >> 5, d = j & 31;
      float4 r4 = make_float4(acc[0][v], acc[1][v], acc[2][v], acc[3][v]);
      *(float4*)&O1[(((long)b * NHh + h) * HDd + d) * Nn + i0 + tx * 4] = r4;
    } else if (MODE == 2) {
      const float bb = bias[j];
      float4 r4 = make_float4(acc[0][v] + bb, acc[1][v] + bb, acc[2][v] + bb, acc[3][v] + bb);
      *(float4*)&O1[((long)b * Cc + j) * Nn + i0 + tx * 4] = r4;
    } else {
      const int two = j >> 8, jj = j & 255;
      const int h = jj >> 5, d = jj & 31;
      float* p = two ? O2 : O1;
#pragma unroll
      for (int u = 0; u < 4; u++)
        p[(((long)b * NHh + h) * Mm + (i0 + tx * 4 + u)) * HDd + d] = acc[u][v];
    }
  }
}

// ------------- sv[b,h,d] = sum_m v[b,h,m,d] -------------
__launch_bounds__(256)
__global__ void compute_sv(const float* __restrict__ vb, float* __restrict__ sv)
{
  __shared__ float red[256];
  const int bh = blockIdx.x, tid = threadIdx.x;
  const int d = tid & 31, ch = tid >> 5;
  const float* vp = vb + (long)bh * Mm * HDd;
  float s = 0.f;
  for (int m = ch; m < Mm; m += 8) s += vp[m * HDd + d];
  red[tid] = s;
  __syncthreads();
  if (tid < 32) {
    float t = 0.f;
#pragma unroll
    for (int cc = 0; cc < 8; cc++) t += red[cc * 32 + tid];
    sv[(long)bh * HDd + tid] = t;
  }
}

// ------------- scores + softmax -> attn (bf16) -------------
__launch_bounds__(256)
__global__ void attn_softmax(const float* __restrict__ qhT, const float* __restrict__ kb,
                             const float* __restrict__ rpb, unsigned short* __restrict__ attn)
{
  __shared__ __align__(16) float Ks[Mm][36];
  __shared__ __align__(16) float qs[32][36];
  const int b = blockIdx.z, h = blockIdx.y, n0 = blockIdx.x * 32;
  const int tid = threadIdx.x;
  const float* kp = kb + ((long)b * NHh + h) * Mm * HDd;
#pragma unroll
  for (int u = 0; u < 8; u++) {
    const int f = tid + u * 256;
    const int m = f >> 3, d = (f & 7) * 4;
    *(float4*)&Ks[m][d] = *(const float4*)&kp[m * HDd + d];
  }
  const float* qp = qhT + ((long)b * NHh + h) * HDd * Nn;
#pragma unroll
  for (int u = 0; u < 4; u++) {
    const int idx = tid + u * 256;
    const int nn = idx & 31, dd = idx >> 5;
    qs[nn][dd] = qp[(long)dd * Nn + n0 + nn];
  }
  __syncthreads();
  const int lane = tid & 63, w = tid >> 6;
  const int r0 = w * 8;
  float s[8][4] = {};
#pragma unroll
  for (int dq = 0; dq < 8; dq++) {
    float4 k4[4];
#pragma unroll
    for (int j = 0; j < 4; j++) k4[j] = *(const float4*)&Ks[lane + j * 64][dq * 4];
#pragma unroll
    for (int r = 0; r < 8; r++) {
      const float4 q4 = *(const float4*)&qs[r0 + r][dq * 4];
#pragma unroll
      for (int j = 0; j < 4; j++) {
        s[r][j] = fmaf(q4.x, k4[j].x, s[r][j]);
        s[r][j] = fmaf(q4.y, k4[j].y, s[r][j]);
        s[r][j] = fmaf(q4.z, k4[j].z, s[r][j]);
        s[r][j] = fmaf(q4.w, k4[j].w, s[r][j]);
      }
    }
  }
#pragma unroll
  for (int r = 0; r < 8; r++) {
    const int n = n0 + r0 + r;
    const float* rp = rpb + (long)n * Mm;
    float sc[4];
#pragma unroll
    for (int j = 0; j < 4; j++) sc[j] = fmaf(s[r][j], SCALEf, rp[lane + j * 64]);
    float mx = fmaxf(fmaxf(sc[0], sc[1]), fmaxf(sc[2], sc[3]));
    mx = wave_max(mx);
    float e[4], sum = 0.f;
#pragma unroll
    for (int j = 0; j < 4; j++) { e[j] = __expf(sc[j] - mx); sum += e[j]; }
    sum = wave_sum(sum);
    const float inv = 1.f / sum;
    unsigned short* ap = attn + (((long)b * NHh + h) * Nn + n) * Mm;
#pragma unroll
    for (int j = 0; j < 4; j++) ap[lane + j * 64] = f2bf(e[j] * inv);
  }
}

// ------------- Gram matrix G[b][36*STP] (line-spread atomics) -------------
__launch_bounds__(256)
__global__ void gram_stats(const unsigned short* __restrict__ attn, float* __restrict__ G)
{
  __shared__ float red[36][4];
  const int b = blockIdx.y, tid = threadIdx.x;
  const unsigned short* ap = attn + (long)b * NHh * NMs + (long)blockIdx.x * 2048 + tid * 8;
  float a[8][8];
#pragma unroll
  for (int h = 0; h < 8; h++) {
    const uint4 v = *(const uint4*)&ap[(long)h * NMs];
    a[h][0] = bflo(v.x); a[h][1] = bfhi(v.x); a[h][2] = bflo(v.y); a[h][3] = bfhi(v.y);
    a[h][4] = bflo(v.z); a[h][5] = bfhi(v.z); a[h][6] = bflo(v.w); a[h][7] = bfhi(v.w);
  }
  float g[36];
  int t = 0;
#pragma unroll
  for (int i = 0; i < 8; i++)
#pragma unroll
    for (int j = i; j < 8; j++, t++) {
      float s = 0.f;
#pragma unroll
      for (int m = 0; m < 8; m++) s = fmaf(a[i][m], a[j][m], s);
      g[t] = s;
    }
  const int lane = tid & 63, wid = tid >> 6;
#pragma unroll
  for (int t2 = 0; t2 < 36; t2++) {
    const float s = wave_sum(g[t2]);
    if (lane == 0) red[t2][wid] = s;
  }
  __syncthreads();
  if (tid < 36)
    atomicAdd(&G[((long)b * 36 + tid) * STP],
              red[tid][0] + red[tid][1] + red[tid][2] + red[tid][3]);
}

// ------------- pass B: expand+gn1(from G)+swish -> conv3x3 -> x2(bf16) + gn2 stats ----
// One-shot staging: all 18 halo rows into 72 KB LDS with all 768 threads,
// ONE barrier, then each wave runs the full row loop barrier-free from LDS.
// Grid (64, CHUNK): R8's proven traffic-clean geometry, 2 blocks/CU.
__launch_bounds__(768)
__global__ void dla_pass_b(const unsigned short* __restrict__ attn,
                           const float* __restrict__ Wexp,
                           const float* __restrict__ g1, const float* __restrict__ b1,
                           const float* __restrict__ G, const float* __restrict__ Wdw,
                           unsigned short* __restrict__ x2, float* __restrict__ stats2c, int b0)
{
  __shared__ __align__(16) unsigned short sl[TTB + 2][NHh][Mm];   // 18 x 4 KB = 72 KB
  const int tid = threadIdx.x;
  const int wv = tid >> 6, lane = tid & 63;
  const int bc = blockIdx.y, b = b0 + bc;
  const int n0 = blockIdx.x * TTB;
  const int c0 = wv * 2;
  const int g = c0 >> 3;
  // gn1 stats from Gram matrix (mean exact: softmax rows sum to 1)
  float mu, rs;
  {
    const float* Gb = G + (long)b * 36 * STP;
    float sum = 0.f, sumsq = 0.f;
    for (int c = g * 8; c < g * 8 + 8; c++) {
      float w[8];
#pragma unroll
      for (int h = 0; h < 8; h++) w[h] = Wexp[c * 8 + h];
      float wsu = 0.f;
#pragma unroll
      for (int h = 0; h < 8; h++) wsu += w[h];
      sum += wsu;
      float s2 = 0.f;
      int t = 0;
#pragma unroll
      for (int i = 0; i < 8; i++)
#pragma unroll
        for (int j = i; j < 8; j++, t++) {
          const float f = (i == j) ? 1.f : 2.f;
          s2 = fmaf(f * w[i] * w[j], Gb[t * STP], s2);
        }
      sumsq += s2;
    }
    const float cnt = 8.f * NMs;
    mu = sum * ((float)Nn / cnt);
    const float var = sumsq / cnt - mu * mu;
    rs = rsqrtf(var + EPSf);
  }
  float we[2][8], B1f[2], wd[2][9];
#pragma unroll
  for (int j = 0; j < 2; j++) {
    const int c = c0 + j;
    const float A1 = rs * g1[c];
    B1f[j] = b1[c] - mu * A1;
#pragma unroll
    for (int h = 0; h < NHh; h++) we[j][h] = Wexp[c * NHh + h] * A1;
#pragma unroll
    for (int k = 0; k < 9; k++) wd[j][k] = Wdw[c * 9 + k];
  }
  // stage all 18 rows: 18*8*32 = 4608 uint4s, 6 per thread, coalesced
  const unsigned short* ab = attn + (long)b * NHh * NMs;
#pragma unroll
  for (int k = 0; k < 6; k++) {
    const int f = tid + k * 768;
    const int row = f >> 8;
    const int rem = f & 255;
    const int h = rem >> 5, seg = rem & 31;
    const int nn = n0 - 1 + row;
    uint4 v = make_uint4(0u, 0u, 0u, 0u);
    if (nn >= 0 && nn < Nn)
      v = *(const uint4*)&ab[(long)h * NMs + (long)nn * Mm + seg * 8];
    *(uint4*)&sl[row][h][seg * 8] = v;
  }
  __syncthreads();   // the only barrier: all rows staged
  float s1[2][4] = {}, s2v[2][4] = {};
  float sm[2] = {}, sq[2] = {};
  for (int r = -1; r <= TTB; r++) {
    const int nn = n0 + r;
    const bool rowv = (nn >= 0 && nn < Nn);
    float af[8][4];
#pragma unroll
    for (int h = 0; h < NHh; h++) {
      const ushort4 v = *(const ushort4*)&sl[r + 1][h][lane * 4];
      af[h][0] = bfup(v.x); af[h][1] = bfup(v.y);
      af[h][2] = bfup(v.z); af[h][3] = bfup(v.w);
    }
#pragma unroll
    for (int j = 0; j < 2; j++) {
      float x1[4];
      if (rowv) {
#pragma unroll
        for (int mi = 0; mi < 4; mi++) {
          float x = B1f[j];
#pragma unroll
          for (int h = 0; h < NHh; h++) x = fmaf(we[j][h], af[h][mi], x);
          x1[mi] = swish_(x);
        }
      } else {
#pragma unroll
        for (int mi = 0; mi < 4; mi++) x1[mi] = 0.f;
      }
      float xl = __shfl_up(x1[3], 1);
      float xr = __shfl_down(x1[0], 1);
      if (lane == 0) xl = 0.f;
      if (lane == 63) xr = 0.f;
      const float L[4]  = {xl, x1[0], x1[1], x1[2]};
      const float Ce[4] = {x1[0], x1[1], x1[2], x1[3]};
      const float R[4]  = {x1[1], x1[2], x1[3], xr};
      float y[4];
#pragma unroll
      for (int mi = 0; mi < 4; mi++) {
        const float u0 = wd[j][0]*L[mi] + wd[j][1]*Ce[mi] + wd[j][2]*R[mi];
        const float u1 = wd[j][3]*L[mi] + wd[j][4]*Ce[mi] + wd[j][5]*R[mi];
        const float u2 = wd[j][6]*L[mi] + wd[j][7]*Ce[mi] + wd[j][8]*R[mi];
        y[mi] = s2v[j][mi] + u2;
        s2v[j][mi] = s1[j][mi] + u1;
        s1[j][mi] = u0;
      }
      if (r >= 1) {
#pragma unroll
        for (int mi = 0; mi < 4; mi++) { sm[j] += y[mi]; sq[j] = fmaf(y[mi], y[mi], sq[j]); }
        ushort4 st;
        st.x = f2bf(y[0]); st.y = f2bf(y[1]); st.z = f2bf(y[2]); st.w = f2bf(y[3]);
        const int nw = n0 + r - 1;
        *(ushort4*)&x2[((long)(bc * Nn + nw) * HIDh + (c0 + j)) * Mm + lane * 4] = st;
      }
    }
  }
#pragma unroll
  for (int j = 0; j < 2; j++) {
    const float vs = wave_sum(sm[j]);
    const float vq = wave_sum(sq[j]);
    if (lane == 0) {
      atomicAdd(&stats2c[((long)b * HIDh + c0 + j) * STP], vs);
      atomicAdd(&stats2c[((long)b * HIDh + c0 + j) * STP + 1], vq);
    }
  }
}

// ------------- pass C: gn2+swish + 1x1 reduce -> a2(bf16) + partial gn3 stats -------
__launch_bounds__(256)
__global__ void dla_pass_c(const unsigned short* __restrict__ x2, const float* __restrict__ g2,
                           const float* __restrict__ b2, const float* __restrict__ stats2c,
                           const float* __restrict__ Wred, unsigned short* __restrict__ a2,
                           float* __restrict__ partial3, int b0)
{
  __shared__ float wA[HIDh], wB[HIDh], wrs[HIDh][NHh];
  __shared__ float red2[2][4];
  const int tid = threadIdx.x;
  const int wv = tid >> 6, lane = tid & 63;
  const int bc = blockIdx.y, b = b0 + bc;
  if (tid < HIDh) {
    const int c = tid, g = c >> 3;
    float s = 0.f, q = 0.f;
#pragma unroll
    for (int cc = 0; cc < 8; cc++) {
      s += stats2c[((long)b * HIDh + g * 8 + cc) * STP];
      q += stats2c[((long)b * HIDh + g * 8 + cc) * STP + 1];
    }
    const float cnt = 8.f * NMs;
    const float mu = s / cnt;
    const float var = q / cnt - mu * mu;
    const float A2 = rsqrtf(var + EPSf) * g2[c];
    wA[c] = A2; wB[c] = b2[c] - mu * A2;
  }
  if (tid < HIDh * NHh) {
    const int c = tid >> 3, h = tid & 7;
    wrs[c][h] = Wred[h * HIDh + c];
  }
  __syncthreads();
  const int n = blockIdx.x * 4 + wv;
  const unsigned short* xp = x2 + (long)(bc * Nn + n) * HIDh * Mm + lane * 4;
  float red[NHh][4] = {};
#pragma unroll
  for (int c = 0; c < HIDh; c++) {
    const ushort4 xv = *(const ushort4*)&xp[c * Mm];
    const float Ac = wA[c], Bc = wB[c];
    float sw[4];
    sw[0] = swish_(fmaf(bfup(xv.x), Ac, Bc));
    sw[1] = swish_(fmaf(bfup(xv.y), Ac, Bc));
    sw[2] = swish_(fmaf(bfup(xv.z), Ac, Bc));
    sw[3] = swish_(fmaf(bfup(xv.w), Ac, Bc));
#pragma unroll
    for (int h = 0; h < NHh; h++) {
      const float w = wrs[c][h];
      red[h][0] = fmaf(w, sw[0], red[h][0]);
      red[h][1] = fmaf(w, sw[1], red[h][1]);
      red[h][2] = fmaf(w, sw[2], red[h][2]);
      red[h][3] = fmaf(w, sw[3], red[h][3]);
    }
  }
  float s3 = 0.f, q3 = 0.f;
#pragma unroll
  for (int h = 0; h < NHh; h++) {
    ushort4 st;
    st.x = f2bf(red[h][0]); st.y = f2bf(red[h][1]);
    st.z = f2bf(red[h][2]); st.w = f2bf(red[h][3]);
    *(ushort4*)&a2[(((long)b * NHh + h) * Nn + n) * Mm + lane * 4] = st;
#pragma unroll
    for (int mi = 0; mi < 4; mi++) {
      s3 += red[h][mi]; q3 = fmaf(red[h][mi], red[h][mi], q3);
    }
  }
  s3 = wave_sum(s3); q3 = wave_sum(q3);
  if (lane == 0) { red2[0][wv] = s3; red2[1][wv] = q3; }
  __syncthreads();
  if (tid < 2) {
    float t = red2[tid][0] + red2[tid][1] + red2[tid][2] + red2[tid][3];
    partial3[((long)b * 256 + blockIdx.x) * 2 + tid] = t;
  }
}

// ------------- finalize gn3 stats: reduce partial3[b][256][2] -> stats3[b][2] -------
__launch_bounds__(256)
__global__ void finalize_stats3(const float* __restrict__ partial3, float* __restrict__ stats3)
{
  __shared__ float red2[2][4];
  const int b = blockIdx.x, tid = threadIdx.x;
  const int lane = tid & 63, wv = tid >> 6;
  float s = partial3[((long)b * 256 + tid) * 2];
  float q = partial3[((long)b * 256 + tid) * 2 + 1];
  s = wave_sum(s); q = wave_sum(q);
  if (lane == 0) { red2[0][wv] = s; red2[1][wv] = q; }
  __syncthreads();
  if (tid < 2)
    stats3[b * 2 + tid] = red2[tid][0] + red2[tid][1] + red2[tid][2] + red2[tid][3];
}

// ------------- pv_out: gn3 (folded) + PV -> oT[b,c,n] (coalesced) -------------
__launch_bounds__(256)
__global__ void pv_out(const unsigned short* __restrict__ a2, const float* __restrict__ vb,
                       const float* __restrict__ sv, const float* __restrict__ stats3,
                       const float* __restrict__ g3, const float* __restrict__ b3,
                       float* __restrict__ o)
{
  __shared__ __align__(16) float As[16 * 260];
  __shared__ __align__(16) float Vs[Mm * HDd];
  const int b = blockIdx.z, h = blockIdx.y, n0 = blockIdx.x * 256;
  const int tid = threadIdx.x;
  const float* vp = vb + ((long)b * NHh + h) * Mm * HDd;
#pragma unroll
  for (int u = 0; u < 8; u++) {
    const int f = tid + u * 256;
    ((float4*)Vs)[f] = ((const float4*)vp)[f];
  }
  const unsigned short* ap = a2 + (((long)b * NHh + h) * Nn + n0) * Mm;
  const int tx = tid & 63, ty = tid >> 6;
  float acc[4][8] = {};
  for (int k0 = 0; k0 < Mm; k0 += 16) {
    __syncthreads();
#pragma unroll
    for (int u = 0; u < 2; u++) {
      const int s = tid + u * 256;
      const int row = s >> 1, half = (s & 1) * 8;
      const uint4 pk = *(const uint4*)(ap + (long)row * Mm + k0 + half);
      As[(half + 0) * 260 + row] = bflo(pk.x);
      As[(half + 1) * 260 + row] = bfhi(pk.x);
      As[(half + 2) * 260 + row] = bflo(pk.y);
      As[(half + 3) * 260 + row] = bfhi(pk.y);
      As[(half + 4) * 260 + row] = bflo(pk.z);
      As[(half + 5) * 260 + row] = bfhi(pk.z);
      As[(half + 6) * 260 + row] = bflo(pk.w);
      As[(half + 7) * 260 + row] = bfhi(pk.w);
    }
    __syncthreads();
#pragma unroll
    for (int k = 0; k < 16; k++) {
      const float4 a4 = *(const float4*)&As[k * 260 + tx * 4];
      const float4 w0 = *(const float4*)&Vs[(k0 + k) * HDd + ty * 8];
      const float4 w1 = *(const float4*)&Vs[(k0 + k) * HDd + ty * 8 + 4];
      const float av[4] = {a4.x, a4.y, a4.z, a4.w};
      const float vv[8] = {w0.x, w0.y, w0.z, w0.w, w1.x, w1.y, w1.z, w1.w};
#pragma unroll
      for (int u = 0; u < 4; u++)
#pragma unroll
        for (int v = 0; v < 8; v++)
          acc[u][v] = fmaf(av[u], vv[v], acc[u][v]);
    }
  }
  const float cnt = (float)(NHh * NMs);
  const float mu = stats3[b * 2] / cnt;
  const float var = stats3[b * 2 + 1] / cnt - mu * mu;
  const float r3 = rsqrtf(var + EPSf);
  const float alpha = r3 * g3[h];
  const float beta = b3[h] - mu * alpha;
  float svv[8];
#pragma unroll
  for (int v = 0; v < 8; v++) svv[v] = sv[((long)b * NHh + h) * HDd + ty * 8 + v];
#pragma unroll
  for (int v = 0; v < 8; v++) {
    const int c = h * HDd + ty * 8 + v;
    const float bv = beta * svv[v];
    float4 r4 = make_float4(fmaf(alpha, acc[0][v], bv), fmaf(alpha, acc[1][v], bv),
                            fmaf(alpha, acc[2][v], bv), fmaf(alpha, acc[3][v], bv));
    *(float4*)&o[((long)b * Cc + c) * Nn + n0 + tx * 4] = r4;
  }
}

extern "C" void kernel_launch(void* const* d_in, const int* in_sizes, int n_in,
                              void* d_out, int out_size, void* d_ws, size_t ws_size,
                              hipStream_t stream) {
  const float* q    = (const float*)d_in[0];
  const float* kv   = (const float*)d_in[1];
  const float* Wq   = (const float*)d_in[2];
  const float* Wkv  = (const float*)d_in[3];
  const float* Wp   = (const float*)d_in[4];
  const float* bp   = (const float*)d_in[5];
  const float* rpb  = (const float*)d_in[6];
  const float* Wexp = (const float*)d_in[7];
  const float* g1   = (const float*)d_in[8];
  const float* b1   = (const float*)d_in[9];
  const float* Wdw  = (const float*)d_in[10];
  const float* g2   = (const float*)d_in[11];
  const float* b2   = (const float*)d_in[12];
  const float* Wred = (const float*)d_in[13];
  const float* g3   = (const float*)d_in[14];
  const float* b3   = (const float*)d_in[15];
  float* out = (float*)d_out;

  float* ws = (float*)d_ws;
  size_t off = 0;
  auto alloc = [&](size_t n) { float* p = ws + off; off += n; return p; };
  float* attnf   = alloc((size_t)Bb * NHh * NMs / 2);      // 67.1 MB (bf16)
  float* a2f     = alloc((size_t)Bb * NHh * NMs / 2);      // 67.1 MB (bf16)
  float* big     = alloc((size_t)CHUNK * HIDh * NMs / 2);  // 100.7 MB: qhT -> x2 -> oT
  float* kbuf    = alloc((size_t)Bb * NHh * Mm * HDd);     // 4.2 MB
  float* vbuf    = alloc((size_t)Bb * NHh * Mm * HDd);     // 4.2 MB
  float* sv      = alloc((size_t)Bb * NHh * HDd);
  float* G       = alloc((size_t)Bb * 36 * STP);           // line-spread
  float* stats2c = alloc((size_t)Bb * HIDh * STP);         // line-spread
  float* stats3  = alloc(Bb * 2);
  float* partial3= alloc((size_t)Bb * 256 * 2);            // fully overwritten, no memset
  unsigned short* attn = (unsigned short*)attnf;
  unsigned short* a2 = (unsigned short*)a2f;
  float* qhT = big;                           // dead after attn_softmax
  unsigned short* x2 = (unsigned short*)big;  // alive during DLA chunk loop
  float* oT = big;                            // alive after last pass C

  // zero only the atomic-accumulated buffers (G | stats2c are contiguous)
  hipMemsetAsync(G, 0, (size_t)(Bb * 36 * STP + Bb * HIDh * STP) * sizeof(float), stream);

  gemm_tn<0><<<dim3(Nn / 64, Cc / 64, Bb), 256, 0, stream>>>(
      q, Wq, nullptr, qhT, nullptr, Cc, (long)Cc * Nn, Nn, 1);
  gemm_tn<1><<<dim3(Mm / 64, 512 / 64, Bb), 256, 0, stream>>>(
      kv, Wkv, nullptr, kbuf, vbuf, Cc, (long)Cc * Mm, Mm, 1);
  compute_sv<<<dim3(Bb * NHh), 256, 0, stream>>>(vbuf, sv);
  attn_softmax<<<dim3(Nn / 32, NHh, Bb), 256, 0, stream>>>(qhT, kbuf, rpb, attn);
  gram_stats<<<dim3(NMs / 2048, Bb), 256, 0, stream>>>(attn, G);

  for (int b0 = 0; b0 < Bb; b0 += CHUNK) {
    dla_pass_b<<<dim3(Nn / TTB, CHUNK), 768, 0, stream>>>(
        attn, Wexp, g1, b1, G, Wdw, x2, stats2c, b0);
    dla_pass_c<<<dim3(Nn / 4, CHUNK), 256, 0, stream>>>(
        x2, g2, b2, stats2c, Wred, a2, partial3, b0);
  }
  finalize_stats3<<<dim3(Bb), 256, 0, stream>>>(partial3, stats3);

  pv_out<<<dim3(Nn / 256, NHh, Bb), 256, 0, stream>>>(a2, vbuf, sv, stats3, g3, b3, oT);
  gemm_tn<2><<<dim3(Nn / 64, Cc / 64, Bb), 256, 0, stream>>>(
      oT, Wp, bp, out, nullptr, Cc, (long)Cc * Nn, Nn, 1);
}